// Round 7
// baseline (1215.554 us; speedup 1.0000x reference)
//
#include <hip/hip_runtime.h>
#include <hip/hip_cooperative_groups.h>
#include <math.h>

namespace cg = cooperative_groups;

#define NN 16384
#define NP 8192
#define NL 8192
#define KW 32
#define VC 100000
#define NSWEEP 12
#define CLEAN_EPOCH 1000

__device__ __forceinline__ float sigmoidf_(float x){ return 1.0f/(1.0f+expf(-x)); }

// ---- K1: fused setup: E-transpose + 6 weight transposes + done/g_rem init ----
__global__ void __launch_bounds__(256) k_setup(const float* __restrict__ E, float* __restrict__ ET,
    const float* __restrict__ Wz, const float* __restrict__ Wr, const float* __restrict__ Wh,
    const float* __restrict__ Uz, const float* __restrict__ Ur, const float* __restrict__ Uh,
    float* __restrict__ WT, int* done, int* g_rem, int et_blocks){
  __shared__ float tile[64][65];
  int b = blockIdx.x;
  int lane = threadIdx.x & 63, ty = threadIdx.x >> 6;
  if (b < et_blocks){
    int v0 = b*64;
    for (int h = ty; h < 64; h += 4){
      int v = v0 + lane;
      tile[h][lane] = (v < VC) ? E[(size_t)h*VC + v] : 0.f;
    }
    __syncthreads();
    for (int vv = ty; vv < 64; vv += 4){
      int v = v0 + vv;
      if (v < VC) ET[v*64 + lane] = tile[lane][vv];
    }
  } else if (b < et_blocks + 6){
    int m = b - et_blocks;
    const float* src = (m==0)?Wz:(m==1)?Wr:(m==2)?Wh:(m==3)?Uz:(m==4)?Ur:Uh;
    float* dst = WT + m*4096;
    for (int h = ty; h < 64; h += 4) tile[h][lane] = src[h*64 + lane];
    __syncthreads();
    for (int k = ty; k < 64; k += 4) dst[k*64 + lane] = tile[lane][k];
  } else {
    int idx = (b - et_blocks - 6)*256 + threadIdx.x;
    if (idx < NP) done[idx] = 0;
    if (idx == 0) *g_rem = NP;
  }
}

// ---------------- K2a: xe = einsum over gathered ET rows ----------------
__global__ void k_xe(const float* __restrict__ xw, const int* __restrict__ xi,
                     const float* __restrict__ ET, float* __restrict__ xe){
  int wid = blockIdx.x*(blockDim.x>>6) + (threadIdx.x>>6);
  int lane = threadIdx.x & 63;
  if (wid >= NN) return;
  int   idxl = (lane < KW) ? xi[wid*KW + lane] : 0;
  float wl   = (lane < KW) ? xw[wid*KW + lane] : 0.f;
  float acc = 0.f;
  #pragma unroll 8
  for (int k = 0; k < KW; ++k){
    int   vk = __shfl(idxl, k);
    float wk = __shfl(wl,   k);
    acc += wk * ET[vk*64 + lane];
  }
  xe[wid*64 + lane] = acc;
}

// K2b fallback: strided gather from E (only if ws too small for ET)
__global__ void k_xe_direct(const float* __restrict__ xw, const int* __restrict__ xi,
                            const float* __restrict__ E, float* __restrict__ xe){
  int wid = blockIdx.x*(blockDim.x>>6) + (threadIdx.x>>6);
  int lane = threadIdx.x & 63;
  if (wid >= NN) return;
  const float* w = xw + wid*KW;
  const int*   v = xi + wid*KW;
  const float* Erow = E + (size_t)lane*VC;
  float acc = 0.f;
  for (int k = 0; k < KW; ++k){
    acc += w[k] * Erow[v[k]];
  }
  xe[wid*64 + lane] = acc;
}

// -------- K3: fused node transform (leaf GRU + parent precompute) --------
__global__ void __launch_bounds__(256) k_node(const float* __restrict__ xe,
    const float* __restrict__ WzT, const float* __restrict__ WrT,
    const float* __restrict__ WhT, const float* __restrict__ Wa,
    const float* __restrict__ bz, const float* __restrict__ br,
    const float* __restrict__ bh,
    float* __restrict__ node_h, float* __restrict__ pz, float* __restrict__ pr,
    float* __restrict__ pc, float* __restrict__ qa){
  int wid = blockIdx.x*(blockDim.x>>6) + (threadIdx.x>>6);
  int lane = threadIdx.x & 63;
  if (wid >= NN) return;
  float xev = xe[wid*64 + lane];
  if (wid < NL){
    float az0=0.f, az1=0.f, ah0=0.f, ah1=0.f;
    #pragma unroll 8
    for (int k=0;k<64;k+=2){
      float x0 = __shfl(xev, k), x1 = __shfl(xev, k+1);
      az0 += x0 * WzT[k*64+lane];     az1 += x1 * WzT[(k+1)*64+lane];
      ah0 += x0 * WhT[k*64+lane];     ah1 += x1 * WhT[(k+1)*64+lane];
    }
    float z = sigmoidf_(az0+az1 + bz[lane]);
    float c = tanhf(ah0+ah1 + bh[lane]);
    node_h[wid*64+lane] = (1.f-z)*c;
  } else {
    int i = wid - NL;
    float az=0.f, ar=0.f, ah=0.f, aq=0.f;
    #pragma unroll 4
    for (int k=0;k<64;++k){
      float xk = __shfl(xev, k);
      az += xk * WzT[k*64+lane];
      ar += xk * WrT[k*64+lane];
      ah += xk * WhT[k*64+lane];
      aq += xk * Wa [k*64+lane];
    }
    pz[i*64+lane] = az + bz[lane];
    pr[i*64+lane] = ar + br[lane];
    pc[i*64+lane] = ah + bh[lane];
    qa[i*64+lane] = aq;
  }
}

// ---------------- shared per-parent GRU step (no LDS, split chains) ----------------
__device__ __forceinline__ void gru_parent(int i, int lane,
    int c0,int c1,int c2,int c3,
    const float* __restrict__ qa, const float* __restrict__ pz,
    const float* __restrict__ pr, const float* __restrict__ pc,
    const float* __restrict__ UzT, const float* __restrict__ UrT,
    const float* __restrict__ UhT, float* node_h)
{
  float chv0 = (c0>=0)? node_h[c0*64+lane] : 0.f;
  float chv1 = (c1>=0)? node_h[c1*64+lane] : 0.f;
  float chv2 = (c2>=0)? node_h[c2*64+lane] : 0.f;
  float chv3 = (c3>=0)? node_h[c3*64+lane] : 0.f;
  float q = qa[i*64+lane];
  float d0=q*chv0, d1=q*chv1, d2=q*chv2, d3=q*chv3;
  #pragma unroll
  for (int off=32; off; off>>=1){
    d0 += __shfl_xor(d0, off); d1 += __shfl_xor(d1, off);
    d2 += __shfl_xor(d2, off); d3 += __shfl_xor(d3, off);
  }
  float l0 = (c0>=0)? sigmoidf_(d0) : -1e30f;
  float l1 = (c1>=0)? sigmoidf_(d1) : -1e30f;
  float l2 = (c2>=0)? sigmoidf_(d2) : -1e30f;
  float l3 = (c3>=0)? sigmoidf_(d3) : -1e30f;
  float mx = fmaxf(fmaxf(l0,l1), fmaxf(l2,l3));
  float e0=expf(l0-mx), e1=expf(l1-mx), e2=expf(l2-mx), e3=expf(l3-mx);
  float inv = 1.f/(e0+e1+e2+e3);
  float ht = (e0*chv0 + e1*chv1 + e2*chv2 + e3*chv3)*inv;   // h_tilde[lane]
  float az0=0.f, az1=0.f, ar0=0.f, ar1=0.f;
  #pragma unroll 8
  for (int k=0;k<64;k+=2){
    float h0 = __shfl(ht, k), h1 = __shfl(ht, k+1);
    az0 += h0 * UzT[k*64+lane];     az1 += h1 * UzT[(k+1)*64+lane];
    ar0 += h0 * UrT[k*64+lane];     ar1 += h1 * UrT[(k+1)*64+lane];
  }
  float z = sigmoidf_(pz[i*64+lane] + az0+az1);
  float r = sigmoidf_(pr[i*64+lane] + ar0+ar1);
  float rh = r*ht;
  float ac0=0.f, ac1=0.f, ac2=0.f, ac3=0.f;
  #pragma unroll 8
  for (int k=0;k<64;k+=4){
    float r0 = __shfl(rh, k),   r1 = __shfl(rh, k+1);
    float r2 = __shfl(rh, k+2), r3 = __shfl(rh, k+3);
    ac0 += r0 * UhT[k*64+lane];     ac1 += r1 * UhT[(k+1)*64+lane];
    ac2 += r2 * UhT[(k+2)*64+lane]; ac3 += r3 * UhT[(k+3)*64+lane];
  }
  float cc = tanhf(pc[i*64+lane] + (ac0+ac1)+(ac2+ac3));
  node_h[(NL+i)*64+lane] = z*ht + (1.f-z)*cc;
}

__device__ __forceinline__ bool lvl_ready(int c, int lvl, const int* done){
  if (c < NL) return true;              // no child (-1) or leaf
  int e = done[c - NL];
  return (e > 0 && e < lvl);            // strictly earlier level only
}

// ---- K4: cooperative scan: all levels in ONE kernel + fused max-pool + head ----
// 1024 blocks x 256 thr (4 blocks/CU co-resident). Wave w of block b owns parents
// wid and wid+4096. Strict level discipline (same semantics as the proven sweeps);
// grid.sync() provides cross-XCD visibility between levels; U/tree/done stay L2-hot.
__global__ void __launch_bounds__(256) k_coop(const int* __restrict__ tree,
    const float* __restrict__ qa, const float* __restrict__ pz,
    const float* __restrict__ pr, const float* __restrict__ pc,
    const float* __restrict__ UzT, const float* __restrict__ UrT,
    const float* __restrict__ UhT,
    float* node_h, int* done, int* g_rem,
    const float* __restrict__ Wout, const float* __restrict__ bout,
    float* __restrict__ out, float* __restrict__ partial)
{
  cg::grid_group grid = cg::this_grid();
  __shared__ float sm[4][64];
  int w = threadIdx.x >> 6, lane = threadIdx.x & 63;
  int wid = blockIdx.x*4 + w;           // 0..4095
  int p0 = wid, p1 = wid + 4096;
  const int* t0 = tree + p0*5;
  const int* t1 = tree + p1*5;
  int a0=t0[0], a1=t0[1], a2=t0[2], a3=t0[3];
  int b0=t1[0], b1=t1[1], b2=t1[2], b3=t1[3];
  bool d0=false, d1=false;
  for (int lvl = 1; lvl <= 64; ++lvl){
    if (!d0 && lvl_ready(a0,lvl,done) && lvl_ready(a1,lvl,done)
            && lvl_ready(a2,lvl,done) && lvl_ready(a3,lvl,done)){
      gru_parent(p0, lane, a0,a1,a2,a3, qa,pz,pr,pc, UzT,UrT,UhT, node_h);
      if (lane==0){ done[p0] = lvl; atomicAdd(g_rem, -1); }
      d0 = true;
    }
    if (!d1 && lvl_ready(b0,lvl,done) && lvl_ready(b1,lvl,done)
            && lvl_ready(b2,lvl,done) && lvl_ready(b3,lvl,done)){
      gru_parent(p1, lane, b0,b1,b2,b3, qa,pz,pr,pc, UzT,UrT,UhT, node_h);
      if (lane==0){ done[p1] = lvl; atomicAdd(g_rem, -1); }
      d1 = true;
    }
    grid.sync();                         // level barrier: full cross-XCD visibility
    if (*g_rem == 0) break;              // uniform decision across the grid
  }
  // ---- fused max-pool over parent rows ----
  {
    int base = NL + blockIdx.x*8 + w*2;
    float m = fmaxf(node_h[(size_t)base*64+lane], node_h[(size_t)(base+1)*64+lane]);
    sm[w][lane] = m;
    __syncthreads();
    if (w==0){
      m = fmaxf(fmaxf(sm[0][lane],sm[1][lane]), fmaxf(sm[2][lane],sm[3][lane]));
      partial[blockIdx.x*64+lane] = m;
    }
  }
  grid.sync();
  if (blockIdx.x == 0){
    float m = -1e30f;
    for (int r = w; r < 1024; r += 4)
      m = fmaxf(m, partial[r*64+lane]);
    sm[w][lane] = m;
    __syncthreads();
    if (w == 0){
      m = fmaxf(fmaxf(sm[0][lane],sm[1][lane]), fmaxf(sm[2][lane],sm[3][lane]));
      float s0 = Wout[0*64+lane]*m, s1 = Wout[1*64+lane]*m;
      float s2 = Wout[2*64+lane]*m, s3 = Wout[3*64+lane]*m;
      #pragma unroll
      for (int off=32; off; off>>=1){
        s0 += __shfl_xor(s0, off); s1 += __shfl_xor(s1, off);
        s2 += __shfl_xor(s2, off); s3 += __shfl_xor(s3, off);
      }
      s0 += bout[0]; s1 += bout[1]; s2 += bout[2]; s3 += bout[3];
      float mx = fmaxf(fmaxf(s0,s1), fmaxf(s2,s3));
      float e0=expf(s0-mx), e1=expf(s1-mx), e2=expf(s2-mx), e3=expf(s3-mx);
      float inv = 1.f/(e0+e1+e2+e3);
      if (lane==0){
        out[0]=e0*inv; out[1]=e1*inv; out[2]=e2*inv; out[3]=e3*inv;
      }
    }
  }
}

// ------------- Fallback path (only if cooperative launch fails) -------------
__global__ void __launch_bounds__(256) k_sweep(const int* __restrict__ tree,
    const float* __restrict__ qa, const float* __restrict__ pz,
    const float* __restrict__ pr, const float* __restrict__ pc,
    const float* __restrict__ UzT, const float* __restrict__ UrT,
    const float* __restrict__ UhT,
    float* node_h, int* done, int* g_rem, int sweep_id)
{
  if (*g_rem == 0) return;
  int w = threadIdx.x >> 6, lane = threadIdx.x & 63;
  int i = blockIdx.x*4 + w;
  if (i >= NP || done[i]) return;
  const int* tr = tree + i*5;
  int c0=tr[0], c1=tr[1], c2=tr[2], c3=tr[3];
  if (!(lvl_ready(c0,sweep_id,done) && lvl_ready(c1,sweep_id,done)
     && lvl_ready(c2,sweep_id,done) && lvl_ready(c3,sweep_id,done))) return;
  gru_parent(i, lane, c0,c1,c2,c3, qa,pz,pr,pc, UzT,UrT,UhT, node_h);
  if (lane==0){ done[i] = sweep_id; atomicAdd(g_rem, -1); }
}

__global__ void __launch_bounds__(256) k_cleanup(const int* __restrict__ tree,
    const float* __restrict__ qa, const float* __restrict__ pz,
    const float* __restrict__ pr, const float* __restrict__ pc,
    const float* __restrict__ UzT, const float* __restrict__ UrT,
    const float* __restrict__ UhT,
    float* node_h, int* done, int* g_rem)
{
  int rem = *g_rem;
  if (rem <= 0) return;
  __shared__ int cnt_s;
  int w = threadIdx.x >> 6, lane = threadIdx.x & 63;
  int epoch = CLEAN_EPOCH;
  while (rem > 0){
    if (threadIdx.x == 0) cnt_s = 0;
    __syncthreads();
    int my = 0;
    for (int i = w; i < NP; i += 4){
      if (done[i]) continue;
      const int* tr = tree + i*5;
      int c0=tr[0], c1=tr[1], c2=tr[2], c3=tr[3];
      if (!(lvl_ready(c0,epoch,done) && lvl_ready(c1,epoch,done)
         && lvl_ready(c2,epoch,done) && lvl_ready(c3,epoch,done))) continue;
      gru_parent(i, lane, c0,c1,c2,c3, qa,pz,pr,pc, UzT,UrT,UhT, node_h);
      if (lane==0) done[i] = epoch;
      ++my;
    }
    if (lane==0 && my) atomicAdd(&cnt_s, my);
    __syncthreads();
    rem -= cnt_s;
    ++epoch;
    __syncthreads();
  }
}

__global__ void k_max1(const float* __restrict__ node_h, float* __restrict__ partial){
  __shared__ float sm[4][64];
  int lane = threadIdx.x & 63, w = threadIdx.x>>6;
  int base = NL + blockIdx.x*128;
  float m = -1e30f;
  for (int r = w; r < 128; r += 4)
    m = fmaxf(m, node_h[(base+r)*64 + lane]);
  sm[w][lane] = m;
  __syncthreads();
  if (w==0){
    m = fmaxf(fmaxf(sm[0][lane],sm[1][lane]), fmaxf(sm[2][lane],sm[3][lane]));
    partial[blockIdx.x*64+lane] = m;
  }
}

__global__ void k_max2(const float* __restrict__ partial, const float* __restrict__ Wout,
                       const float* __restrict__ bout, float* __restrict__ out){
  int lane = threadIdx.x;
  float m = -1e30f;
  for (int b=0;b<64;++b) m = fmaxf(m, partial[b*64+lane]);
  float s0 = Wout[0*64+lane]*m;
  float s1 = Wout[1*64+lane]*m;
  float s2 = Wout[2*64+lane]*m;
  float s3 = Wout[3*64+lane]*m;
  #pragma unroll
  for (int off=32; off; off>>=1){
    s0 += __shfl_xor(s0, off);
    s1 += __shfl_xor(s1, off);
    s2 += __shfl_xor(s2, off);
    s3 += __shfl_xor(s3, off);
  }
  s0 += bout[0]; s1 += bout[1]; s2 += bout[2]; s3 += bout[3];
  float mx = fmaxf(fmaxf(s0,s1), fmaxf(s2,s3));
  float e0=expf(s0-mx), e1=expf(s1-mx), e2=expf(s2-mx), e3=expf(s3-mx);
  float inv = 1.f/(e0+e1+e2+e3);
  if (lane==0){
    out[0]=e0*inv; out[1]=e1*inv; out[2]=e2*inv; out[3]=e3*inv;
  }
}

__global__ void k_ws_sentinel(float* out, float wsmb){
  if (threadIdx.x < 4) out[threadIdx.x] = wsmb;
}

extern "C" void kernel_launch(void* const* d_in, const int* in_sizes, int n_in,
                              void* d_out, int out_size, void* d_ws, size_t ws_size,
                              hipStream_t stream){
  const float* x_word = (const float*)d_in[0];
  const int*   x_index= (const int*)d_in[1];
  const int*   tree   = (const int*)d_in[2];
  const float* E      = (const float*)d_in[3];
  const float* Wz     = (const float*)d_in[4];
  const float* Uz     = (const float*)d_in[5];
  const float* bz     = (const float*)d_in[6];
  const float* Wr     = (const float*)d_in[7];
  const float* Ur     = (const float*)d_in[8];
  const float* br     = (const float*)d_in[9];
  const float* Wh     = (const float*)d_in[10];
  const float* Uh     = (const float*)d_in[11];
  const float* bh     = (const float*)d_in[12];
  const float* Wa     = (const float*)d_in[13];
  const float* Wout   = (const float*)d_in[14];
  const float* bout   = (const float*)d_in[15];
  float* out = (float*)d_out;

  float* ws = (float*)d_ws;

  // full layout:  [ET 6,400,000 | xe 1,048,576 | nodeh 1,048,576 | WT 24,576 | done 8,192 | g_rem 1]
  //   qa/pz/pr/pc (2,097,152) + part (65,536) ALIAS the ET region (ET dead after k_xe).
  // fb layout (no ET): [qa..pc 2,097,152 | part 65,536 | xe | nodeh | WT | done | g_rem]
  const size_t FULL_NEED = (size_t)(6400000 + 1048576 + 1048576 + 24576 + 8192 + 1) * 4; // ~34.1 MB
  const size_t FB_NEED   = (size_t)(2097152 + 65536 + 1048576 + 1048576 + 24576 + 8192 + 1) * 4; // ~17.2 MB

  bool full = (ws_size >= FULL_NEED);
  bool fb   = (!full && ws_size >= FB_NEED);
  if (!full && !fb){
    k_ws_sentinel<<<1, 64, 0, stream>>>(out, (float)(ws_size >> 20));
    return;
  }

  float* qa   = ws;                         // 4 x 524,288
  float* pz   = qa + 524288;
  float* pr   = pz + 524288;
  float* pc   = pr + 524288;
  float* part = pc + 524288;                // 65,536 f
  float* ET   = ws;                         // full path only; dead after k_xe
  size_t tail = full ? (size_t)6400000 : (size_t)(2097152 + 65536);
  float* xe    = ws + tail;                 // 1,048,576 f
  float* nodeh = xe + 1048576;              // 1,048,576 f
  float* WT    = nodeh + 1048576;           // 24,576 f (NOT aliased; written in k_setup)
  int*   done  = (int*)(WT + 24576);        // 8,192 i
  int*   g_rem = done + NP;                 // 1 i
  float* WzT = WT,       *WrT = WT+4096,  *WhT = WT+8192;
  float* UzT = WT+12288, *UrT = WT+16384, *UhT = WT+20480;

  int et_blocks = full ? (VC+63)/64 : 0;    // 1563 or 0
  k_setup<<<et_blocks + 6 + 32, 256, 0, stream>>>(E, ET, Wz, Wr, Wh, Uz, Ur, Uh,
                                                  WT, done, g_rem, et_blocks);
  if (full) k_xe       <<<NN/4, 256, 0, stream>>>(x_word, x_index, ET, xe);
  else      k_xe_direct<<<NN/4, 256, 0, stream>>>(x_word, x_index, E, xe);
  k_node<<<NN/4, 256, 0, stream>>>(xe, WzT, WrT, WhT, Wa, bz, br, bh,
                                   nodeh, pz, pr, pc, qa);

  // Single cooperative kernel: all levels + max-pool + head.
  void* args[] = { (void*)&tree, (void*)&qa, (void*)&pz, (void*)&pr, (void*)&pc,
                   (void*)&UzT, (void*)&UrT, (void*)&UhT,
                   (void*)&nodeh, (void*)&done, (void*)&g_rem,
                   (void*)&Wout, (void*)&bout, (void*)&out, (void*)&part };
  hipError_t err = hipLaunchCooperativeKernel((void*)k_coop, dim3(1024), dim3(256),
                                              args, 0, stream);
  if (err != hipSuccess){
    // Proven multi-dispatch fallback.
    for (int s = 1; s <= NSWEEP; ++s)
      k_sweep<<<NP/4, 256, 0, stream>>>(tree, qa, pz, pr, pc, UzT, UrT, UhT,
                                        nodeh, done, g_rem, s);
    k_cleanup<<<1,  256, 0, stream>>>(tree, qa, pz, pr, pc, UzT, UrT, UhT,
                                      nodeh, done, g_rem);
    k_max1   <<<64, 256, 0, stream>>>(nodeh, part);
    k_max2   <<<1,   64, 0, stream>>>(part, Wout, bout, out);
  }
}

// Round 8
// 259.076 us; speedup vs baseline: 4.6919x; 4.6919x over previous
//
#include <hip/hip_runtime.h>
#include <math.h>

#define NN 16384
#define NP 8192
#define NL 8192
#define KW 32
#define VC 100000
#define NSWEEP 13
#define REVW 8
#define CLEAN_EPOCH 1000

__device__ __forceinline__ float sigmoidf_(float x){ return 1.0f/(1.0f+expf(-x)); }

// ---- K1: fused setup: E-transpose + 6 weight transposes + scheduling state ----
// rcnt/fcnt are pre-zeroed by hipMemsetAsync before this kernel.
__global__ void __launch_bounds__(256) k_setup(const float* __restrict__ E, float* __restrict__ ET,
    const float* __restrict__ Wz, const float* __restrict__ Wr, const float* __restrict__ Wh,
    const float* __restrict__ Uz, const float* __restrict__ Ur, const float* __restrict__ Uh,
    float* __restrict__ WT, const int* __restrict__ tree,
    int* pending, int* done, int* rcnt, int* rev, int* fcnt, int* fr0, int* g_rem,
    int et_blocks){
  __shared__ float tile[64][65];
  int b = blockIdx.x;
  int lane = threadIdx.x & 63, ty = threadIdx.x >> 6;
  if (b < et_blocks){
    int v0 = b*64;
    for (int h = ty; h < 64; h += 4){
      int v = v0 + lane;
      tile[h][lane] = (v < VC) ? E[(size_t)h*VC + v] : 0.f;
    }
    __syncthreads();
    for (int vv = ty; vv < 64; vv += 4){
      int v = v0 + vv;
      if (v < VC) ET[v*64 + lane] = tile[lane][vv];
    }
  } else if (b < et_blocks + 6){
    int m = b - et_blocks;
    const float* src = (m==0)?Wz:(m==1)?Wr:(m==2)?Wh:(m==3)?Uz:(m==4)?Ur:Uh;
    float* dst = WT + m*4096;
    for (int h = ty; h < 64; h += 4) tile[h][lane] = src[h*64 + lane];
    __syncthreads();
    for (int k = ty; k < 64; k += 4) dst[k*64 + lane] = tile[lane][k];
  } else {
    int idx = (b - et_blocks - 6)*256 + threadIdx.x;   // one thread per parent
    if (idx < NP){
      const int* tr = tree + idx*5;
      int cnt = 0;
      #pragma unroll
      for (int j=0;j<4;++j){
        int c = tr[j];
        if (c >= NL){
          ++cnt;
          int cc = c - NL;
          int slot = atomicAdd(&rcnt[cc], 1);
          if (slot < REVW) rev[cc*REVW + slot] = idx;   // overflow -> cleanup backstop
        }
      }
      pending[idx] = cnt;
      done[idx] = 0;
      if (cnt == 0){ int pos = atomicAdd(&fcnt[0], 1); fr0[pos] = idx; }
      if (idx == 0) *g_rem = NP;
    }
  }
}

// ---------------- K2a: xe = einsum over gathered ET rows ----------------
__global__ void k_xe(const float* __restrict__ xw, const int* __restrict__ xi,
                     const float* __restrict__ ET, float* __restrict__ xe){
  int wid = blockIdx.x*(blockDim.x>>6) + (threadIdx.x>>6);
  int lane = threadIdx.x & 63;
  if (wid >= NN) return;
  int   idxl = (lane < KW) ? xi[wid*KW + lane] : 0;
  float wl   = (lane < KW) ? xw[wid*KW + lane] : 0.f;
  float acc = 0.f;
  #pragma unroll 8
  for (int k = 0; k < KW; ++k){
    int   vk = __shfl(idxl, k);
    float wk = __shfl(wl,   k);
    acc += wk * ET[vk*64 + lane];
  }
  xe[wid*64 + lane] = acc;
}

// K2b fallback: strided gather from E (only if ws too small for ET)
__global__ void k_xe_direct(const float* __restrict__ xw, const int* __restrict__ xi,
                            const float* __restrict__ E, float* __restrict__ xe){
  int wid = blockIdx.x*(blockDim.x>>6) + (threadIdx.x>>6);
  int lane = threadIdx.x & 63;
  if (wid >= NN) return;
  const float* w = xw + wid*KW;
  const int*   v = xi + wid*KW;
  const float* Erow = E + (size_t)lane*VC;
  float acc = 0.f;
  for (int k = 0; k < KW; ++k){
    acc += w[k] * Erow[v[k]];
  }
  xe[wid*64 + lane] = acc;
}

// -------- K3: fused node transform (leaf GRU + parent precompute) --------
__global__ void __launch_bounds__(256) k_node(const float* __restrict__ xe,
    const float* __restrict__ WzT, const float* __restrict__ WrT,
    const float* __restrict__ WhT, const float* __restrict__ Wa,
    const float* __restrict__ bz, const float* __restrict__ br,
    const float* __restrict__ bh,
    float* __restrict__ node_h, float* __restrict__ pz, float* __restrict__ pr,
    float* __restrict__ pc, float* __restrict__ qa){
  int wid = blockIdx.x*(blockDim.x>>6) + (threadIdx.x>>6);
  int lane = threadIdx.x & 63;
  if (wid >= NN) return;
  float xev = xe[wid*64 + lane];
  if (wid < NL){
    float az0=0.f, az1=0.f, ah0=0.f, ah1=0.f;
    #pragma unroll 8
    for (int k=0;k<64;k+=2){
      float x0 = __shfl(xev, k), x1 = __shfl(xev, k+1);
      az0 += x0 * WzT[k*64+lane];     az1 += x1 * WzT[(k+1)*64+lane];
      ah0 += x0 * WhT[k*64+lane];     ah1 += x1 * WhT[(k+1)*64+lane];
    }
    float z = sigmoidf_(az0+az1 + bz[lane]);
    float c = tanhf(ah0+ah1 + bh[lane]);
    node_h[wid*64+lane] = (1.f-z)*c;
  } else {
    int i = wid - NL;
    float az=0.f, ar=0.f, ah=0.f, aq=0.f;
    #pragma unroll 4
    for (int k=0;k<64;++k){
      float xk = __shfl(xev, k);
      az += xk * WzT[k*64+lane];
      ar += xk * WrT[k*64+lane];
      ah += xk * WhT[k*64+lane];
      aq += xk * Wa [k*64+lane];
    }
    pz[i*64+lane] = az + bz[lane];
    pr[i*64+lane] = ar + br[lane];
    pc[i*64+lane] = ah + bh[lane];
    qa[i*64+lane] = aq;
  }
}

// ---------------- shared per-parent GRU step (no LDS, split chains) ----------------
__device__ __forceinline__ void gru_parent(int i, int lane,
    int c0,int c1,int c2,int c3,
    const float* __restrict__ qa, const float* __restrict__ pz,
    const float* __restrict__ pr, const float* __restrict__ pc,
    const float* __restrict__ UzT, const float* __restrict__ UrT,
    const float* __restrict__ UhT, float* node_h)
{
  float chv0 = (c0>=0)? node_h[c0*64+lane] : 0.f;
  float chv1 = (c1>=0)? node_h[c1*64+lane] : 0.f;
  float chv2 = (c2>=0)? node_h[c2*64+lane] : 0.f;
  float chv3 = (c3>=0)? node_h[c3*64+lane] : 0.f;
  float q = qa[i*64+lane];
  float d0=q*chv0, d1=q*chv1, d2=q*chv2, d3=q*chv3;
  #pragma unroll
  for (int off=32; off; off>>=1){
    d0 += __shfl_xor(d0, off); d1 += __shfl_xor(d1, off);
    d2 += __shfl_xor(d2, off); d3 += __shfl_xor(d3, off);
  }
  float l0 = (c0>=0)? sigmoidf_(d0) : -1e30f;
  float l1 = (c1>=0)? sigmoidf_(d1) : -1e30f;
  float l2 = (c2>=0)? sigmoidf_(d2) : -1e30f;
  float l3 = (c3>=0)? sigmoidf_(d3) : -1e30f;
  float mx = fmaxf(fmaxf(l0,l1), fmaxf(l2,l3));
  float e0=expf(l0-mx), e1=expf(l1-mx), e2=expf(l2-mx), e3=expf(l3-mx);
  float inv = 1.f/(e0+e1+e2+e3);
  float ht = (e0*chv0 + e1*chv1 + e2*chv2 + e3*chv3)*inv;   // h_tilde[lane]
  float az0=0.f, az1=0.f, ar0=0.f, ar1=0.f;
  #pragma unroll 8
  for (int k=0;k<64;k+=2){
    float h0 = __shfl(ht, k), h1 = __shfl(ht, k+1);
    az0 += h0 * UzT[k*64+lane];     az1 += h1 * UzT[(k+1)*64+lane];
    ar0 += h0 * UrT[k*64+lane];     ar1 += h1 * UrT[(k+1)*64+lane];
  }
  float z = sigmoidf_(pz[i*64+lane] + az0+az1);
  float r = sigmoidf_(pr[i*64+lane] + ar0+ar1);
  float rh = r*ht;
  float ac0=0.f, ac1=0.f, ac2=0.f, ac3=0.f;
  #pragma unroll 8
  for (int k=0;k<64;k+=4){
    float r0 = __shfl(rh, k),   r1 = __shfl(rh, k+1);
    float r2 = __shfl(rh, k+2), r3 = __shfl(rh, k+3);
    ac0 += r0 * UhT[k*64+lane];     ac1 += r1 * UhT[(k+1)*64+lane];
    ac2 += r2 * UhT[(k+2)*64+lane]; ac3 += r3 * UhT[(k+3)*64+lane];
  }
  float cc = tanhf(pc[i*64+lane] + (ac0+ac1)+(ac2+ac3));
  node_h[(NL+i)*64+lane] = z*ht + (1.f-z)*cc;
}

__device__ __forceinline__ bool lvl_ready(int c, int lvl, const int* done){
  if (c < NL) return true;              // no child (-1) or leaf
  int e = done[c - NL];
  return (e > 0 && e < lvl);            // strictly earlier dispatch only
}

// ---------------- K4: frontier sweep (exact worklist, one wave per entry) ----------------
// Entries in frIn were enqueued in an EARLIER dispatch, when their last parent-child
// completed -> all children node_h are visible across the dispatch boundary. No polling.
__global__ void __launch_bounds__(256) k_front(const int* __restrict__ tree,
    const float* __restrict__ qa, const float* __restrict__ pz,
    const float* __restrict__ pr, const float* __restrict__ pc,
    const float* __restrict__ UzT, const float* __restrict__ UrT,
    const float* __restrict__ UhT,
    float* node_h, int* done, int* g_rem,
    int* pending, const int* __restrict__ rcnt, const int* __restrict__ rev,
    int* fcnt, const int* __restrict__ frIn, int* frOut, int s)
{
  int cnt = fcnt[s];
  int w = threadIdx.x >> 6, lane = threadIdx.x & 63;
  int wid = blockIdx.x*4 + w;
  if (wid >= cnt) return;
  int i = frIn[wid];
  const int* tr = tree + i*5;
  gru_parent(i, lane, tr[0],tr[1],tr[2],tr[3], qa,pz,pr,pc, UzT,UrT,UhT, node_h);
  if (lane == 0){
    done[i] = s + 1;
    atomicAdd(g_rem, -1);
    int rc = rcnt[i]; if (rc > REVW) rc = REVW;
    for (int j = 0; j < rc; ++j){
      int cons = rev[i*REVW + j];
      if (atomicSub(&pending[cons], 1) == 1){       // last child just completed
        int pos = atomicAdd(&fcnt[s+1], 1);
        frOut[pos] = cons;
      }
    }
  }
}

// ------------- K5: single-block cleanup (guaranteed termination, proven) -------------
__global__ void __launch_bounds__(256) k_cleanup(const int* __restrict__ tree,
    const float* __restrict__ qa, const float* __restrict__ pz,
    const float* __restrict__ pr, const float* __restrict__ pc,
    const float* __restrict__ UzT, const float* __restrict__ UrT,
    const float* __restrict__ UhT,
    float* node_h, int* done, int* g_rem)
{
  int rem = *g_rem;
  if (rem <= 0) return;
  __shared__ int cnt_s;
  int w = threadIdx.x >> 6, lane = threadIdx.x & 63;
  int epoch = CLEAN_EPOCH;
  while (rem > 0){
    if (threadIdx.x == 0) cnt_s = 0;
    __syncthreads();
    int my = 0;
    for (int i = w; i < NP; i += 4){
      if (done[i]) continue;
      const int* tr = tree + i*5;
      int c0=tr[0], c1=tr[1], c2=tr[2], c3=tr[3];
      if (!(lvl_ready(c0,epoch,done) && lvl_ready(c1,epoch,done)
         && lvl_ready(c2,epoch,done) && lvl_ready(c3,epoch,done))) continue;
      gru_parent(i, lane, c0,c1,c2,c3, qa,pz,pr,pc, UzT,UrT,UhT, node_h);
      if (lane==0) done[i] = epoch;
      ++my;
    }
    if (lane==0 && my) atomicAdd(&cnt_s, my);
    __syncthreads();
    rem -= cnt_s;
    ++epoch;
    __syncthreads();
  }
}

// ---------------- K6a/K6b: max-pool + head ----------------
__global__ void k_max1(const float* __restrict__ node_h, float* __restrict__ partial){
  __shared__ float sm[4][64];
  int lane = threadIdx.x & 63, w = threadIdx.x>>6;
  int base = NL + blockIdx.x*128;
  float m = -1e30f;
  for (int r = w; r < 128; r += 4)
    m = fmaxf(m, node_h[(size_t)(base+r)*64 + lane]);
  sm[w][lane] = m;
  __syncthreads();
  if (w==0){
    m = fmaxf(fmaxf(sm[0][lane],sm[1][lane]), fmaxf(sm[2][lane],sm[3][lane]));
    partial[blockIdx.x*64+lane] = m;
  }
}

__global__ void k_max2(const float* __restrict__ partial, const float* __restrict__ Wout,
                       const float* __restrict__ bout, float* __restrict__ out){
  int lane = threadIdx.x;   // 64 threads = 1 wave
  float m = -1e30f;
  for (int b=0;b<64;++b) m = fmaxf(m, partial[b*64+lane]);
  float s0 = Wout[0*64+lane]*m;
  float s1 = Wout[1*64+lane]*m;
  float s2 = Wout[2*64+lane]*m;
  float s3 = Wout[3*64+lane]*m;
  #pragma unroll
  for (int off=32; off; off>>=1){
    s0 += __shfl_xor(s0, off);
    s1 += __shfl_xor(s1, off);
    s2 += __shfl_xor(s2, off);
    s3 += __shfl_xor(s3, off);
  }
  s0 += bout[0]; s1 += bout[1]; s2 += bout[2]; s3 += bout[3];
  float mx = fmaxf(fmaxf(s0,s1), fmaxf(s2,s3));
  float e0=expf(s0-mx), e1=expf(s1-mx), e2=expf(s2-mx), e3=expf(s3-mx);
  float inv = 1.f/(e0+e1+e2+e3);
  if (lane==0){
    out[0]=e0*inv; out[1]=e1*inv; out[2]=e2*inv; out[3]=e3*inv;
  }
}

__global__ void k_ws_sentinel(float* out, float wsmb){
  if (threadIdx.x < 4) out[threadIdx.x] = wsmb;
}

extern "C" void kernel_launch(void* const* d_in, const int* in_sizes, int n_in,
                              void* d_out, int out_size, void* d_ws, size_t ws_size,
                              hipStream_t stream){
  const float* x_word = (const float*)d_in[0];
  const int*   x_index= (const int*)d_in[1];
  const int*   tree   = (const int*)d_in[2];
  const float* E      = (const float*)d_in[3];
  const float* Wz     = (const float*)d_in[4];
  const float* Uz     = (const float*)d_in[5];
  const float* bz     = (const float*)d_in[6];
  const float* Wr     = (const float*)d_in[7];
  const float* Ur     = (const float*)d_in[8];
  const float* br     = (const float*)d_in[9];
  const float* Wh     = (const float*)d_in[10];
  const float* Uh     = (const float*)d_in[11];
  const float* bh     = (const float*)d_in[12];
  const float* Wa     = (const float*)d_in[13];
  const float* Wout   = (const float*)d_in[14];
  const float* bout   = (const float*)d_in[15];
  float* out = (float*)d_out;

  float* ws = (float*)d_ws;

  // region0: ET (6,400,000 f) during {setup, xe}. After k_xe, ET is dead and region0
  // is re-used for qa/pz/pr/pc (2,097,152) + part (4,096) + nodeh (1,048,576).
  // Tail (never aliased): xe | WT | done | g_rem | pending | rcnt | fcnt | fr0 | fr1 | rev.
  const size_t R0_FULL = 6400000;
  const size_t R0_FB   = 3149824;            // qa..pc + part + nodeh
  const size_t TAIL    = 1048576 + 24576 + (NP + 1 + NP + NP + 16 + NP + NP + NP*REVW);
  const size_t FULL_NEED = (R0_FULL + TAIL) * 4;   // ~28.9 MB  (< proven-available 34.1 MB)
  const size_t FB_NEED   = (R0_FB   + TAIL) * 4;   // ~17.3 MB

  bool full = (ws_size >= FULL_NEED);
  bool fb   = (!full && ws_size >= FB_NEED);
  if (!full && !fb){
    k_ws_sentinel<<<1, 64, 0, stream>>>(out, (float)(ws_size >> 20));
    return;
  }

  float* qa    = ws;                        // 4 x 524,288
  float* pz    = qa + 524288;
  float* pr    = pz + 524288;
  float* pc    = pr + 524288;
  float* part  = pc + 524288;               // 4,096 f      (@2,097,152)
  float* nodeh = part + 4096;               // 1,048,576 f  (@2,101,248)
  float* ET    = ws;                        // full path only; dead after k_xe
  size_t r0    = full ? R0_FULL : R0_FB;
  float* xe    = ws + r0;                   // 1,048,576 f
  float* WT    = xe + 1048576;              // 24,576 f
  int*   done    = (int*)(WT + 24576);      // NP
  int*   g_rem   = done + NP;               // 1
  int*   pending = g_rem + 1;               // NP
  int*   rcnt    = pending + NP;            // NP
  int*   fcnt    = rcnt + NP;               // 16   (contiguous with rcnt for one memset)
  int*   fr0     = fcnt + 16;               // NP
  int*   fr1     = fr0 + NP;                // NP
  int*   rev     = fr1 + NP;                // NP*REVW
  float* WzT = WT,       *WrT = WT+4096,  *WhT = WT+8192;
  float* UzT = WT+12288, *UrT = WT+16384, *UhT = WT+20480;

  // zero the atomic counters consumed by k_setup (rcnt + fcnt are contiguous)
  hipMemsetAsync(rcnt, 0, (NP + 16)*sizeof(int), stream);

  int et_blocks = full ? (VC+63)/64 : 0;    // 1563 or 0
  k_setup<<<et_blocks + 6 + NP/256, 256, 0, stream>>>(E, ET, Wz, Wr, Wh, Uz, Ur, Uh,
                                                      WT, tree, pending, done, rcnt,
                                                      rev, fcnt, fr0, g_rem, et_blocks);
  if (full) k_xe       <<<NN/4, 256, 0, stream>>>(x_word, x_index, ET, xe);
  else      k_xe_direct<<<NN/4, 256, 0, stream>>>(x_word, x_index, E, xe);
  k_node<<<NN/4, 256, 0, stream>>>(xe, WzT, WrT, WhT, Wa, bz, br, bh,
                                   nodeh, pz, pr, pc, qa);
  for (int s = 0; s < NSWEEP; ++s){
    const int* frIn  = (s & 1) ? fr1 : fr0;
    int*       frOut = (s & 1) ? fr0 : fr1;
    k_front<<<NP/4, 256, 0, stream>>>(tree, qa, pz, pr, pc, UzT, UrT, UhT,
                                      nodeh, done, g_rem, pending, rcnt, rev,
                                      fcnt, frIn, frOut, s);
  }
  k_cleanup<<<1,  256, 0, stream>>>(tree, qa, pz, pr, pc, UzT, UrT, UhT,
                                    nodeh, done, g_rem);
  k_max1   <<<64, 256, 0, stream>>>(nodeh, part);
  k_max2   <<<1,   64, 0, stream>>>(part, Wout, bout, out);
}